// Round 14
// baseline (152.184 us; speedup 1.0000x reference)
//
#include <hip/hip_runtime.h>
#include <hip/hip_bf16.h>

// GenePathwayTransformerEncoder on MI355X (gfx950)
// B=16, G=2000, P=512, D=128, H=4, dh=32, L=2
// v14 = v12 (passing: plain-__syncthreads double-buffered megakernel,
// RESIDENT u8 gate registers) + ONE change: __launch_bounds__(256, 1).
// Occupancy is LDS-capped at 2 blocks/CU for any VGPR<=256, so the previous
// (256,2) 128-reg allocator target (158 B/thread scratch, WRITE_SIZE 20MB)
// bought nothing. NOTE: gate streaming is BANNED — it NaN'd in both v10
// (asm protocol) and v13 (syncthreads protocol); resident gate passes.

typedef __attribute__((ext_vector_type(8))) short s16x8;
typedef __attribute__((ext_vector_type(4))) float f32x4;

static __device__ __forceinline__ unsigned short f2bf(float f) {
  union { float f; unsigned u; } v; v.f = f;
  unsigned r = v.u + 0x7fff + ((v.u >> 16) & 1);
  return (unsigned short)(r >> 16);
}
static __device__ __forceinline__ unsigned cvtpk(float lo, float hi) {
  unsigned r;
  asm("v_cvt_pk_bf16_f32 %0, %1, %2" : "=v"(r) : "v"(lo), "v"(hi));
  return r;
}
static __device__ __forceinline__ float exp2a(float x) {
  float r;
  asm("v_exp_f32 %0, %1" : "=v"(r) : "v"(x));
  return r;
}
static __device__ __forceinline__ float ub2f(unsigned w, int r) {
  return (float)((w >> (8 * r)) & 0xffu);   // folds to v_cvt_f32_ubyteN
}
static __device__ __forceinline__ s16x8 pack4(unsigned a, unsigned b, unsigned c, unsigned d) {
  union { unsigned u[4]; s16x8 v; } t;
  t.u[0] = a; t.u[1] = b; t.u[2] = c; t.u[3] = d;
  return t.v;
}
static __device__ __forceinline__ void gll16(const void* g, void* l) {
  __builtin_amdgcn_global_load_lds((const __attribute__((address_space(1))) void*)g,
                                   (__attribute__((address_space(3))) void*)l, 16, 0, 0);
}

// ---- weight tables: id = l*4 + {0:WqF kappa2-frag, 1:WkT plain-T, 2:WvT plain-T, 3:WoF kappa2-frag}
__global__ void prep_wt(const float* __restrict__ Wq, const float* __restrict__ Wk,
                        const float* __restrict__ Wv, const float* __restrict__ Wo,
                        unsigned short* __restrict__ WtAll) {
  int id = blockIdx.x;
  int l = id >> 2, type = id & 3;
  const float* W = (type == 0 ? Wq : type == 1 ? Wk : type == 2 ? Wv : Wo) + l * 16384;
  unsigned short* dst = WtAll + id * 16384;
  for (int i = threadIdx.x; i < 16384; i += 256) {
    int k, n;
    if (type == 1 || type == 2) { n = i >> 7; k = i & 127; }
    else {
      int t = i >> 9, lane = (i >> 3) & 63, j = i & 7;
      int nt = t >> 2, c = t & 3, lg = lane >> 4, gg = lane & 15;
      k = c * 32 + lg * 4 + (j & 3) + 16 * (j >> 2);
      n = nt * 16 + gg;
    }
    dst[i] = f2bf(W[k * 128 + n]);
  }
}

// ---- gate, pi-permuted, u8-quantized: Mgu[g][slot] = round(255*sigmoid(...))
__global__ void prep_gate(const int* __restrict__ gene_idx, const float* __restrict__ W_soft,
                          unsigned char* __restrict__ Mgu) {
  int t = blockIdx.x * 256 + threadIdx.x;   // 250*256 = 64000 = 2000*8*4
  int g = t >> 5, sub = (t >> 2) & 7, lg = t & 3;
  int idx = gene_idx[2000 + g];             // reference uses gene_indices[1]
  const float* src = &W_soft[(size_t)idx * 512 + sub * 64 + lg * 8];
  float4 v0 = *(const float4*)&src[0];
  float4 v1 = *(const float4*)&src[4];
  float4 v2 = *(const float4*)&src[32];
  float4 v3 = *(const float4*)&src[36];
  unsigned char tmp[16];
  const float* vs[4] = {&v0.x, &v1.x, &v2.x, &v3.x};
#pragma unroll
  for (int tl = 0; tl < 4; tl++)
#pragma unroll
    for (int r = 0; r < 4; r++)
      tmp[tl * 4 + r] = (unsigned char)rintf(255.f / (1.f + __expf(-vs[tl][r])));
  *(uint4*)(Mgu + (size_t)g * 512 + sub * 64 + lg * 16) = *(const uint4*)tmp;
}

// ---- K/V fragment tables for both layers, pathway gather inline.
__global__ __launch_bounds__(64) void kv_pack(const int* __restrict__ pw_idx,
                                              const float* __restrict__ pw_emb,
                                              const unsigned short* __restrict__ WtAll,
                                              const float* __restrict__ bk,
                                              const float* __restrict__ bv,
                                              unsigned short* __restrict__ KfG,
                                              unsigned short* __restrict__ VfG) {
  int bx = blockIdx.x;                 // 2048 = 2l * 16b * 32pt * 2dh2
  int l = bx >> 10, rest = bx & 1023;
  int b = rest >> 6, r2 = rest & 63;
  int pt = r2 >> 1, dh2 = r2 & 1;
  const unsigned short* WtK = WtAll + (l * 4 + 1) * 16384;
  const unsigned short* WtV = WtAll + (l * 4 + 2) * 16384;
  const float* bkl = bk + l * 128;
  const float* bvl = bv + l * 128;
  int lane = threadIdx.x, lg = lane >> 4, gg = lane & 15;
  int p = pt * 16 + gg;
  int pi = pw_idx[b * 512 + p];
  const float* src = pw_emb + (size_t)pi * 128 + lg * 8;
  s16x8 kxf[4];
#pragma unroll
  for (int c = 0; c < 4; ++c) {
    float4 u0 = *(const float4*)&src[c * 32];
    float4 u1 = *(const float4*)&src[c * 32 + 4];
    kxf[c] = pack4(cvtpk(u0.x, u0.y), cvtpk(u0.z, u0.w), cvtpk(u1.x, u1.y), cvtpk(u1.z, u1.w));
  }
  int tg = 4 * (p >> 6) + 2 * ((p >> 5) & 1) + ((p >> 2) & 1);
  int q  = 4 * ((p >> 3) & 3) + (p & 3);
#pragma unroll
  for (int dtl = 0; dtl < 4; ++dtl) {
    int dt = dh2 * 4 + dtl;
    f32x4 acc = (f32x4){0.f, 0.f, 0.f, 0.f};
#pragma unroll
    for (int c = 0; c < 4; ++c) {
      s16x8 wf = *(const s16x8*)&WtK[(size_t)(16 * dt + gg) * 128 + c * 32 + lg * 8];
      acc = __builtin_amdgcn_mfma_f32_16x16x32_bf16(wf, kxf[c], acc, 0, 0, 0);
    }
    float4 b4 = *(const float4*)&bkl[16 * dt + 4 * lg];
    int h = dt >> 1, u = dt & 1;
    size_t addr = ((((size_t)l * 16 + b) * 4 + h) * 32 + tg) * 512 + (lg * 16 + q) * 8 + 4 * u;
    uint2 st;
    st.x = cvtpk(acc[0] + b4.x, acc[1] + b4.y);
    st.y = cvtpk(acc[2] + b4.z, acc[3] + b4.w);
    *(uint2*)&KfG[addr] = st;
  }
  int cV = pt >> 1, lgpp = 2 * (pt & 1) + (lg >> 1);
#pragma unroll
  for (int ntl = 0; ntl < 4; ++ntl) {
    int nt = dh2 * 4 + ntl;
    f32x4 acc = (f32x4){0.f, 0.f, 0.f, 0.f};
#pragma unroll
    for (int c = 0; c < 4; ++c) {
      s16x8 wf = *(const s16x8*)&WtV[(size_t)(16 * nt + gg) * 128 + c * 32 + lg * 8];
      acc = __builtin_amdgcn_mfma_f32_16x16x32_bf16(kxf[c], wf, acc, 0, 0, 0);
    }
    float bvv = bvl[16 * nt + gg];
    int h = nt >> 1, half = nt & 1;
    size_t addr = (((((size_t)l * 16 + b) * 4 + h) * 2 + half) * 16 + cV) * 512 + (lgpp * 16 + gg) * 8 + 4 * (lg & 1);
    uint2 st;
    st.x = cvtpk(acc[0] + bvv, acc[1] + bvv);
    st.y = cvtpk(acc[2] + bvv, acc[3] + bvv);
    *(uint2*)&VfG[addr] = st;
  }
}

// ---- stage one (h,kc) chunk (16 K-tiles + 16 V-tiles, 1KB each) into LDS buf
static __device__ __forceinline__ void stage_chunk(
    const unsigned short* __restrict__ KfG, const unsigned short* __restrict__ VfG,
    unsigned short* lds0, int buf, int l, int b, int h, int kc, int wave, int lane) {
  unsigned short* base = lds0 + buf * 16384 + wave * 8 * 512;  // wave-uniform
  if (wave < 2) {
    const unsigned short* src =
        KfG + ((((size_t)l * 16 + b) * 4 + h) * 32 + kc * 16 + wave * 8) * 512 + lane * 8;
#pragma unroll
    for (int i = 0; i < 8; ++i) gll16(src + i * 512, base + i * 512);
  } else {
    int half = wave - 2;
    const unsigned short* src =
        VfG + (((((size_t)l * 16 + b) * 4 + h) * 2 + half) * 16 + kc * 8) * 512 + lane * 8;
#pragma unroll
    for (int i = 0; i < 8; ++i) gll16(src + i * 512, base + i * 512);
  }
}

// One QK-tile-quad + gated exp + PV step (gate from resident gu[] registers).
// Accumulates into ov_a / ov_b / ssum declared by enclosing HBLOCK.
#define SCSTEP(MM, SC)                                                          \
  {                                                                             \
    unsigned gw0 = gu[((MM) & 1) * 4 + (SC)].x;                                 \
    unsigned gw1 = gu[((MM) & 1) * 4 + (SC)].y;                                 \
    unsigned gw2 = gu[((MM) & 1) * 4 + (SC)].z;                                 \
    unsigned gw3 = gu[((MM) & 1) * 4 + (SC)].w;                                 \
    f32x4 av0 = __builtin_amdgcn_mfma_f32_16x16x32_bf16(                        \
        *(const s16x8*)&KL[((SC) * 4 + 0) * 512 + lane * 8], qf[(MM) >> 1], zf, 0, 0, 0); \
    f32x4 av1 = __builtin_amdgcn_mfma_f32_16x16x32_bf16(                        \
        *(const s16x8*)&KL[((SC) * 4 + 1) * 512 + lane * 8], qf[(MM) >> 1], zf, 0, 0, 0); \
    f32x4 av2 = __builtin_amdgcn_mfma_f32_16x16x32_bf16(                        \
        *(const s16x8*)&KL[((SC) * 4 + 2) * 512 + lane * 8], qf[(MM) >> 1], zf, 0, 0, 0); \
    f32x4 av3 = __builtin_amdgcn_mfma_f32_16x16x32_bf16(                        \
        *(const s16x8*)&KL[((SC) * 4 + 3) * 512 + lane * 8], qf[(MM) >> 1], zf, 0, 0, 0); \
    float e0, e1, e2, e3;                                                       \
    unsigned p00, p01, p10, p11, p20, p21, p30, p31;                            \
    e0 = exp2a(av0[0] * ub2f(gw0, 0));                                          \
    e1 = exp2a(av0[1] * ub2f(gw0, 1));                                          \
    e2 = exp2a(av0[2] * ub2f(gw0, 2));                                          \
    e3 = exp2a(av0[3] * ub2f(gw0, 3));                                          \
    ssum += (e0 + e1) + (e2 + e3);                                              \
    p00 = cvtpk(e0, e1); p01 = cvtpk(e2, e3);                                   \
    e0 = exp2a(av1[0] * ub2f(gw1, 0));                                          \
    e1 = exp2a(av1[1] * ub2f(gw1, 1));                                          \
    e2 = exp2a(av1[2] * ub2f(gw1, 2));                                          \
    e3 = exp2a(av1[3] * ub2f(gw1, 3));                                          \
    ssum += (e0 + e1) + (e2 + e3);                                              \
    p10 = cvtpk(e0, e1); p11 = cvtpk(e2, e3);                                   \
    e0 = exp2a(av2[0] * ub2f(gw2, 0));                                          \
    e1 = exp2a(av2[1] * ub2f(gw2, 1));                                          \
    e2 = exp2a(av2[2] * ub2f(gw2, 2));                                          \
    e3 = exp2a(av2[3] * ub2f(gw2, 3));                                          \
    ssum += (e0 + e1) + (e2 + e3);                                              \
    p20 = cvtpk(e0, e1); p21 = cvtpk(e2, e3);                                   \
    e0 = exp2a(av3[0] * ub2f(gw3, 0));                                          \
    e1 = exp2a(av3[1] * ub2f(gw3, 1));                                          \
    e2 = exp2a(av3[2] * ub2f(gw3, 2));                                          \
    e3 = exp2a(av3[3] * ub2f(gw3, 3));                                          \
    ssum += (e0 + e1) + (e2 + e3);                                              \
    p30 = cvtpk(e0, e1); p31 = cvtpk(e2, e3);                                   \
    s16x8 pf0 = pack4(p00, p01, p10, p11);                                      \
    s16x8 pf1 = pack4(p20, p21, p30, p31);                                      \
    ov_a = __builtin_amdgcn_mfma_f32_16x16x32_bf16(                             \
        *(const s16x8*)&VL[((SC) * 2 + 0) * 512 + lane * 8], pf0, ov_a, 0, 0, 0); \
    ov_b = __builtin_amdgcn_mfma_f32_16x16x32_bf16(                             \
        *(const s16x8*)&VL[(8 + (SC) * 2 + 0) * 512 + lane * 8], pf0, ov_b, 0, 0, 0); \
    ov_a = __builtin_amdgcn_mfma_f32_16x16x32_bf16(                             \
        *(const s16x8*)&VL[((SC) * 2 + 1) * 512 + lane * 8], pf1, ov_a, 0, 0, 0); \
    ov_b = __builtin_amdgcn_mfma_f32_16x16x32_bf16(                             \
        *(const s16x8*)&VL[(8 + (SC) * 2 + 1) * 512 + lane * 8], pf1, ov_b, 0, 0, 0); \
  }

// m97-style chunk: issue next stage, compute current, ONE __syncthreads().
#define CHUNK(MM)                                                               \
  {                                                                             \
    if ((MM) < 7) stage_chunk(KfG, VfG, lds0, ((MM) + 1) & 1, l, b,             \
                              ((MM) + 1) >> 1, ((MM) + 1) & 1, wave, lane);     \
    const unsigned short* KL = &lds[(MM) & 1][0];                               \
    const unsigned short* VL = &lds[(MM) & 1][8192];                            \
    SCSTEP(MM, 0) SCSTEP(MM, 1) SCSTEP(MM, 2) SCSTEP(MM, 3)                     \
    if ((MM) < 7) __syncthreads();                                              \
  }

// per-head block: acc scoped to exactly this head's two chunks
#define HBLOCK(H)                                                               \
  {                                                                             \
    f32x4 ov_a = zf, ov_b = zf;                                                 \
    float ssum = 0.f;                                                           \
    CHUNK(2 * (H)) CHUNK(2 * (H) + 1)                                           \
    ssum += __shfl_xor(ssum, 16, 64);                                           \
    ssum += __shfl_xor(ssum, 32, 64);                                           \
    float inv = 1.f / ssum;                                                     \
    pfO[H] = pack4(cvtpk(ov_a[0] * inv, ov_a[1] * inv),                         \
                   cvtpk(ov_a[2] * inv, ov_a[3] * inv),                         \
                   cvtpk(ov_b[0] * inv, ov_b[1] * inv),                         \
                   cvtpk(ov_b[2] * inv, ov_b[3] * inv));                        \
  }

// ---- megakernel: both layers. block = (64 g-rows, b), 4 waves x 16 rows.
__global__ __launch_bounds__(256, 1) void mega_kern(
    const int* __restrict__ gene_idx, const float* __restrict__ expr,
    const float* __restrict__ gene_emb, const unsigned short* __restrict__ WtAll,
    const float* __restrict__ bq, const float* __restrict__ bo,
    const unsigned short* __restrict__ KfG, const unsigned short* __restrict__ VfG,
    const unsigned char* __restrict__ Mgu, float* __restrict__ partial) {
  __shared__ unsigned short lds[2][16384];  // 64 KB double buffer
  int bid = blockIdx.x;
  int xcd = bid & 7, wi = bid >> 3;
  int b = xcd * 2 + (wi >> 5);              // each XCD owns 2 b's (KV L2 locality)
  int gt = wi & 31;
  int tid = threadIdx.x, lane = tid & 63, wave = tid >> 6;
  int lg = lane >> 4, gg = lane & 15;
  int grow = gt * 64 + wave * 16 + gg;
  int growc = grow < 2000 ? grow : 1999;
  int row = b * 2000 + growc;
  const f32x4 zf = (f32x4){0.f, 0.f, 0.f, 0.f};
  const float GQ = 0.17677669529663687f * 1.4426950408889634f / 255.f;  // folded into Q

  // gate fragments (pi-permuted, u8): 32 VGPRs, resident (streaming NaNs — v10/v13)
  uint4 gu[8];
  {
    const unsigned char* gbase = Mgu + (size_t)growc * 512 + lg * 16;
#pragma unroll
    for (int sub = 0; sub < 8; ++sub)
      gu[sub] = *(const uint4*)(gbase + sub * 64);
  }
  // x0 fragments in kappa2 slots (d = 32c + 4lg + (j&3) + 16*(j>>2))
  s16x8 xf[4];
  {
    int gi = gene_idx[row];
    float ev = expr[row];
    const float* src = gene_emb + (size_t)gi * 128 + lg * 4;
#pragma unroll
    for (int c = 0; c < 4; ++c) {
      float4 u0 = *(const float4*)&src[c * 32];
      float4 u1 = *(const float4*)&src[c * 32 + 16];
      xf[c] = pack4(cvtpk(u0.x * ev, u0.y * ev), cvtpk(u0.z * ev, u0.w * ev),
                    cvtpk(u1.x * ev, u1.y * ev), cvtpk(u1.z * ev, u1.w * ev));
    }
  }

  unsigned short* lds0 = &lds[0][0];

#pragma unroll 1
  for (int l = 0; l < 2; ++l) {
    const unsigned short* WqFl = WtAll + (l * 4 + 0) * 16384;
    const unsigned short* WoFl = WtAll + (l * 4 + 3) * 16384;
    const float* bql = bq + l * 128;
    const float* bol = bo + l * 128;

    stage_chunk(KfG, VfG, lds0, 0, l, b, 0, 0, wave, lane);  // prefetch chunk 0

    // Q projection (register-only; overlaps chunk-0 load latency)
    s16x8 qf[4];
    {
      f32x4 qacc[8];
#pragma unroll
      for (int nt = 0; nt < 8; ++nt) {
        f32x4 acc = zf;
#pragma unroll
        for (int c = 0; c < 4; ++c) {
          s16x8 wf = *(const s16x8*)&WqFl[((nt * 4 + c) << 9) + lane * 8];
          acc = __builtin_amdgcn_mfma_f32_16x16x32_bf16(wf, xf[c], acc, 0, 0, 0);
        }
        float4 b4 = *(const float4*)&bql[nt * 16 + lg * 4];
        acc[0] = (acc[0] + b4.x) * GQ;
        acc[1] = (acc[1] + b4.y) * GQ;
        acc[2] = (acc[2] + b4.z) * GQ;
        acc[3] = (acc[3] + b4.w) * GQ;
        qacc[nt] = acc;
      }
#pragma unroll
      for (int h = 0; h < 4; ++h)
        qf[h] = pack4(cvtpk(qacc[2 * h][0], qacc[2 * h][1]), cvtpk(qacc[2 * h][2], qacc[2 * h][3]),
                      cvtpk(qacc[2 * h + 1][0], qacc[2 * h + 1][1]), cvtpk(qacc[2 * h + 1][2], qacc[2 * h + 1][3]));
    }
    __syncthreads();   // chunk 0 staged

    s16x8 pfO[4];
    HBLOCK(0) HBLOCK(1) HBLOCK(2) HBLOCK(3)

    // O projection: x^T = WoF * O^T (kappa2), + bo
    f32x4 xacc[8];
#pragma unroll
    for (int nt = 0; nt < 8; ++nt) {
      f32x4 acc = zf;
#pragma unroll
      for (int c = 0; c < 4; ++c) {
        s16x8 wf = *(const s16x8*)&WoFl[((nt * 4 + c) << 9) + lane * 8];
        acc = __builtin_amdgcn_mfma_f32_16x16x32_bf16(wf, pfO[c], acc, 0, 0, 0);
      }
      float4 b4 = *(const float4*)&bol[nt * 16 + lg * 4];
      acc[0] += b4.x; acc[1] += b4.y; acc[2] += b4.z; acc[3] += b4.w;
      xacc[nt] = acc;
    }

    if (l == 0) {
      // x1 stays in registers: rename acc -> kappa2 B-frags for layer-1 Q-proj
#pragma unroll
      for (int c = 0; c < 4; ++c)
        xf[c] = pack4(cvtpk(xacc[2 * c][0], xacc[2 * c][1]), cvtpk(xacc[2 * c][2], xacc[2 * c][3]),
                      cvtpk(xacc[2 * c + 1][0], xacc[2 * c + 1][1]), cvtpk(xacc[2 * c + 1][2], xacc[2 * c + 1][3]));
    } else {
      // fold mean-over-g: f32 column sums -> partial[b][gt][128]
      if (grow >= 2000) {
#pragma unroll
        for (int nt = 0; nt < 8; ++nt) xacc[nt] = zf;
      }
#pragma unroll
      for (int nt = 0; nt < 8; ++nt) {
#pragma unroll
        for (int msk = 1; msk <= 8; msk <<= 1) {
          xacc[nt][0] += __shfl_xor(xacc[nt][0], msk, 64);
          xacc[nt][1] += __shfl_xor(xacc[nt][1], msk, 64);
          xacc[nt][2] += __shfl_xor(xacc[nt][2], msk, 64);
          xacc[nt][3] += __shfl_xor(xacc[nt][3], msk, 64);
        }
      }
      float* red = (float*)lds0;
      __syncthreads();   // all waves done reading LDS K/V buffers
      if (gg == 0) {
#pragma unroll
        for (int nt = 0; nt < 8; ++nt) {
          red[wave * 128 + nt * 16 + lg * 4 + 0] = xacc[nt][0];
          red[wave * 128 + nt * 16 + lg * 4 + 1] = xacc[nt][1];
          red[wave * 128 + nt * 16 + lg * 4 + 2] = xacc[nt][2];
          red[wave * 128 + nt * 16 + lg * 4 + 3] = xacc[nt][3];
        }
      }
      __syncthreads();
      if (tid < 128) {
        float s = red[tid] + red[128 + tid] + red[256 + tid] + red[384 + tid];
        partial[((size_t)b * 32 + gt) * 128 + tid] = s;
      }
    }
  }
}

// ---- out[b][p] = mean_d @ W_out + b_out  (f32)
__global__ void final_out(const float* __restrict__ partial, const float* __restrict__ W_out,
                          const float* __restrict__ b_out, float* __restrict__ out) {
  int b = blockIdx.x, tid = threadIdx.x;
  __shared__ float mean[128];
  if (tid < 128) {
    float s = 0.f;
    for (int c = 0; c < 32; c++) s += partial[((size_t)b * 32 + c) * 128 + tid];
    mean[tid] = s * (1.f / 2000.f);
  }
  __syncthreads();
  for (int p = tid; p < 512; p += 256) {
    float a = b_out[p];
    for (int d = 0; d < 128; d++) a += mean[d] * W_out[d * 512 + p];
    out[b * 512 + p] = a;
  }
}

extern "C" void kernel_launch(void* const* d_in, const int* in_sizes, int n_in,
                              void* d_out, int out_size, void* d_ws, size_t ws_size,
                              hipStream_t stream) {
  const int*   gene_idx = (const int*)d_in[0];
  const float* expr     = (const float*)d_in[1];
  const int*   pw_idx   = (const int*)d_in[2];
  const float* W_soft   = (const float*)d_in[3];
  const float* gene_emb = (const float*)d_in[4];
  const float* pw_emb   = (const float*)d_in[5];
  const float* Wq = (const float*)d_in[6];
  const float* bq = (const float*)d_in[7];
  const float* Wk = (const float*)d_in[8];
  const float* bk = (const float*)d_in[9];
  const float* Wv = (const float*)d_in[10];
  const float* bv = (const float*)d_in[11];
  const float* Wo = (const float*)d_in[12];
  const float* bo = (const float*)d_in[13];
  const float* W_out = (const float*)d_in[14];
  const float* b_out = (const float*)d_in[15];
  float* out = (float*)d_out;

  char* ws = (char*)d_ws;
  size_t off = 0;
  auto alloc = [&](size_t bytes) {
    char* p = ws + off;
    off += (bytes + 255) & ~(size_t)255;
    return p;
  };
  unsigned char*  Mgu   = (unsigned char*)alloc((size_t)2048 * 512);               // 1 MB
  unsigned short* WtAll = (unsigned short*)alloc((size_t)8 * 16384 * 2);           // 256 KB
  unsigned short* KfG   = (unsigned short*)alloc((size_t)2 * 16 * 4 * 32 * 512 * 2);      // 4 MB
  unsigned short* VfG   = (unsigned short*)alloc((size_t)2 * 16 * 4 * 2 * 16 * 512 * 2);  // 4 MB
  float* partial        = (float*)alloc((size_t)16 * 32 * 128 * 4);                // 256 KB

  prep_wt<<<8, 256, 0, stream>>>(Wq, Wk, Wv, Wo, WtAll);
  prep_gate<<<250, 256, 0, stream>>>(gene_idx, W_soft, Mgu);
  kv_pack<<<2048, 64, 0, stream>>>(pw_idx, pw_emb, WtAll, bk, bv, KfG, VfG);
  mega_kern<<<512, 256, 0, stream>>>(gene_idx, expr, gene_emb, WtAll, bq, bo, KfG, VfG, Mgu, partial);
  final_out<<<16, 256, 0, stream>>>(partial, W_out, b_out, out);
}

// Round 15
// 108.684 us; speedup vs baseline: 1.4002x; 1.4002x over previous
//
#include <hip/hip_runtime.h>
#include <hip/hip_bf16.h>

// GenePathwayTransformerEncoder on MI355X (gfx950)
// B=16, G=2000, P=512, D=128, H=4, dh=32, L=2
// v15 = v12 verbatim (session best: 108.87 us). Final configuration:
// - kv_pack precomputes pi/kappa-permuted K/V fragment tables (both layers,
//   pathway gather + Wk/Wv GEMM fused, coalesced uint2 stores)
// - megakernel fuses BOTH transformer layers: Q-proj -> QK^T -> gated
//   softmax (u8 gate, exp2, scale folded into Q) -> PV -> O-proj -> layer 2,
//   all in registers via kappa-slot renaming (zero cross-lane exchange);
//   K/V double-buffered in LDS via global_load_lds, plain __syncthreads.
// - mean-over-g folded into megakernel epilogue; final matvec separate.
// Measured: mega ~95us (VGPR 128 + hidden spill beats every alternative
// tried: 156-reg no-spill = 150us, L2-direct = 141us, vmcnt protocol = same,
// head-split waves = 113-183us). Not roofline (MfmaUtil 8%) — best measured.

typedef __attribute__((ext_vector_type(8))) short s16x8;
typedef __attribute__((ext_vector_type(4))) float f32x4;

static __device__ __forceinline__ unsigned short f2bf(float f) {
  union { float f; unsigned u; } v; v.f = f;
  unsigned r = v.u + 0x7fff + ((v.u >> 16) & 1);
  return (unsigned short)(r >> 16);
}
static __device__ __forceinline__ unsigned cvtpk(float lo, float hi) {
  unsigned r;
  asm("v_cvt_pk_bf16_f32 %0, %1, %2" : "=v"(r) : "v"(lo), "v"(hi));
  return r;
}
static __device__ __forceinline__ float exp2a(float x) {
  float r;
  asm("v_exp_f32 %0, %1" : "=v"(r) : "v"(x));
  return r;
}
static __device__ __forceinline__ float ub2f(unsigned w, int r) {
  return (float)((w >> (8 * r)) & 0xffu);   // folds to v_cvt_f32_ubyteN
}
static __device__ __forceinline__ s16x8 pack4(unsigned a, unsigned b, unsigned c, unsigned d) {
  union { unsigned u[4]; s16x8 v; } t;
  t.u[0] = a; t.u[1] = b; t.u[2] = c; t.u[3] = d;
  return t.v;
}
static __device__ __forceinline__ void gll16(const void* g, void* l) {
  __builtin_amdgcn_global_load_lds((const __attribute__((address_space(1))) void*)g,
                                   (__attribute__((address_space(3))) void*)l, 16, 0, 0);
}

// ---- weight tables: id = l*4 + {0:WqF kappa2-frag, 1:WkT plain-T, 2:WvT plain-T, 3:WoF kappa2-frag}
__global__ void prep_wt(const float* __restrict__ Wq, const float* __restrict__ Wk,
                        const float* __restrict__ Wv, const float* __restrict__ Wo,
                        unsigned short* __restrict__ WtAll) {
  int id = blockIdx.x;
  int l = id >> 2, type = id & 3;
  const float* W = (type == 0 ? Wq : type == 1 ? Wk : type == 2 ? Wv : Wo) + l * 16384;
  unsigned short* dst = WtAll + id * 16384;
  for (int i = threadIdx.x; i < 16384; i += 256) {
    int k, n;
    if (type == 1 || type == 2) { n = i >> 7; k = i & 127; }
    else {
      int t = i >> 9, lane = (i >> 3) & 63, j = i & 7;
      int nt = t >> 2, c = t & 3, lg = lane >> 4, gg = lane & 15;
      k = c * 32 + lg * 4 + (j & 3) + 16 * (j >> 2);
      n = nt * 16 + gg;
    }
    dst[i] = f2bf(W[k * 128 + n]);
  }
}

// ---- gate, pi-permuted, u8-quantized: Mgu[g][slot] = round(255*sigmoid(...))
__global__ void prep_gate(const int* __restrict__ gene_idx, const float* __restrict__ W_soft,
                          unsigned char* __restrict__ Mgu) {
  int t = blockIdx.x * 256 + threadIdx.x;   // 250*256 = 64000 = 2000*8*4
  int g = t >> 5, sub = (t >> 2) & 7, lg = t & 3;
  int idx = gene_idx[2000 + g];             // reference uses gene_indices[1]
  const float* src = &W_soft[(size_t)idx * 512 + sub * 64 + lg * 8];
  float4 v0 = *(const float4*)&src[0];
  float4 v1 = *(const float4*)&src[4];
  float4 v2 = *(const float4*)&src[32];
  float4 v3 = *(const float4*)&src[36];
  unsigned char tmp[16];
  const float* vs[4] = {&v0.x, &v1.x, &v2.x, &v3.x};
#pragma unroll
  for (int tl = 0; tl < 4; tl++)
#pragma unroll
    for (int r = 0; r < 4; r++)
      tmp[tl * 4 + r] = (unsigned char)rintf(255.f / (1.f + __expf(-vs[tl][r])));
  *(uint4*)(Mgu + (size_t)g * 512 + sub * 64 + lg * 16) = *(const uint4*)tmp;
}

// ---- K/V fragment tables for both layers, pathway gather inline.
__global__ __launch_bounds__(64) void kv_pack(const int* __restrict__ pw_idx,
                                              const float* __restrict__ pw_emb,
                                              const unsigned short* __restrict__ WtAll,
                                              const float* __restrict__ bk,
                                              const float* __restrict__ bv,
                                              unsigned short* __restrict__ KfG,
                                              unsigned short* __restrict__ VfG) {
  int bx = blockIdx.x;                 // 2048 = 2l * 16b * 32pt * 2dh2
  int l = bx >> 10, rest = bx & 1023;
  int b = rest >> 6, r2 = rest & 63;
  int pt = r2 >> 1, dh2 = r2 & 1;
  const unsigned short* WtK = WtAll + (l * 4 + 1) * 16384;
  const unsigned short* WtV = WtAll + (l * 4 + 2) * 16384;
  const float* bkl = bk + l * 128;
  const float* bvl = bv + l * 128;
  int lane = threadIdx.x, lg = lane >> 4, gg = lane & 15;
  int p = pt * 16 + gg;
  int pi = pw_idx[b * 512 + p];
  const float* src = pw_emb + (size_t)pi * 128 + lg * 8;
  s16x8 kxf[4];
#pragma unroll
  for (int c = 0; c < 4; ++c) {
    float4 u0 = *(const float4*)&src[c * 32];
    float4 u1 = *(const float4*)&src[c * 32 + 4];
    kxf[c] = pack4(cvtpk(u0.x, u0.y), cvtpk(u0.z, u0.w), cvtpk(u1.x, u1.y), cvtpk(u1.z, u1.w));
  }
  int tg = 4 * (p >> 6) + 2 * ((p >> 5) & 1) + ((p >> 2) & 1);
  int q  = 4 * ((p >> 3) & 3) + (p & 3);
#pragma unroll
  for (int dtl = 0; dtl < 4; ++dtl) {
    int dt = dh2 * 4 + dtl;
    f32x4 acc = (f32x4){0.f, 0.f, 0.f, 0.f};
#pragma unroll
    for (int c = 0; c < 4; ++c) {
      s16x8 wf = *(const s16x8*)&WtK[(size_t)(16 * dt + gg) * 128 + c * 32 + lg * 8];
      acc = __builtin_amdgcn_mfma_f32_16x16x32_bf16(wf, kxf[c], acc, 0, 0, 0);
    }
    float4 b4 = *(const float4*)&bkl[16 * dt + 4 * lg];
    int h = dt >> 1, u = dt & 1;
    size_t addr = ((((size_t)l * 16 + b) * 4 + h) * 32 + tg) * 512 + (lg * 16 + q) * 8 + 4 * u;
    uint2 st;
    st.x = cvtpk(acc[0] + b4.x, acc[1] + b4.y);
    st.y = cvtpk(acc[2] + b4.z, acc[3] + b4.w);
    *(uint2*)&KfG[addr] = st;
  }
  int cV = pt >> 1, lgpp = 2 * (pt & 1) + (lg >> 1);
#pragma unroll
  for (int ntl = 0; ntl < 4; ++ntl) {
    int nt = dh2 * 4 + ntl;
    f32x4 acc = (f32x4){0.f, 0.f, 0.f, 0.f};
#pragma unroll
    for (int c = 0; c < 4; ++c) {
      s16x8 wf = *(const s16x8*)&WtV[(size_t)(16 * nt + gg) * 128 + c * 32 + lg * 8];
      acc = __builtin_amdgcn_mfma_f32_16x16x32_bf16(kxf[c], wf, acc, 0, 0, 0);
    }
    float bvv = bvl[16 * nt + gg];
    int h = nt >> 1, half = nt & 1;
    size_t addr = (((((size_t)l * 16 + b) * 4 + h) * 2 + half) * 16 + cV) * 512 + (lgpp * 16 + gg) * 8 + 4 * (lg & 1);
    uint2 st;
    st.x = cvtpk(acc[0] + bvv, acc[1] + bvv);
    st.y = cvtpk(acc[2] + bvv, acc[3] + bvv);
    *(uint2*)&VfG[addr] = st;
  }
}

// ---- stage one (h,kc) chunk (16 K-tiles + 16 V-tiles, 1KB each) into LDS buf
static __device__ __forceinline__ void stage_chunk(
    const unsigned short* __restrict__ KfG, const unsigned short* __restrict__ VfG,
    unsigned short* lds0, int buf, int l, int b, int h, int kc, int wave, int lane) {
  unsigned short* base = lds0 + buf * 16384 + wave * 8 * 512;  // wave-uniform
  if (wave < 2) {
    const unsigned short* src =
        KfG + ((((size_t)l * 16 + b) * 4 + h) * 32 + kc * 16 + wave * 8) * 512 + lane * 8;
#pragma unroll
    for (int i = 0; i < 8; ++i) gll16(src + i * 512, base + i * 512);
  } else {
    int half = wave - 2;
    const unsigned short* src =
        VfG + (((((size_t)l * 16 + b) * 4 + h) * 2 + half) * 16 + kc * 8) * 512 + lane * 8;
#pragma unroll
    for (int i = 0; i < 8; ++i) gll16(src + i * 512, base + i * 512);
  }
}

// One QK-tile-quad + gated exp + PV step (gate from resident gu[] registers).
// Accumulates into ov_a / ov_b / ssum declared by enclosing HBLOCK.
#define SCSTEP(MM, SC)                                                          \
  {                                                                             \
    unsigned gw0 = gu[((MM) & 1) * 4 + (SC)].x;                                 \
    unsigned gw1 = gu[((MM) & 1) * 4 + (SC)].y;                                 \
    unsigned gw2 = gu[((MM) & 1) * 4 + (SC)].z;                                 \
    unsigned gw3 = gu[((MM) & 1) * 4 + (SC)].w;                                 \
    f32x4 av0 = __builtin_amdgcn_mfma_f32_16x16x32_bf16(                        \
        *(const s16x8*)&KL[((SC) * 4 + 0) * 512 + lane * 8], qf[(MM) >> 1], zf, 0, 0, 0); \
    f32x4 av1 = __builtin_amdgcn_mfma_f32_16x16x32_bf16(                        \
        *(const s16x8*)&KL[((SC) * 4 + 1) * 512 + lane * 8], qf[(MM) >> 1], zf, 0, 0, 0); \
    f32x4 av2 = __builtin_amdgcn_mfma_f32_16x16x32_bf16(                        \
        *(const s16x8*)&KL[((SC) * 4 + 2) * 512 + lane * 8], qf[(MM) >> 1], zf, 0, 0, 0); \
    f32x4 av3 = __builtin_amdgcn_mfma_f32_16x16x32_bf16(                        \
        *(const s16x8*)&KL[((SC) * 4 + 3) * 512 + lane * 8], qf[(MM) >> 1], zf, 0, 0, 0); \
    float e0, e1, e2, e3;                                                       \
    unsigned p00, p01, p10, p11, p20, p21, p30, p31;                            \
    e0 = exp2a(av0[0] * ub2f(gw0, 0));                                          \
    e1 = exp2a(av0[1] * ub2f(gw0, 1));                                          \
    e2 = exp2a(av0[2] * ub2f(gw0, 2));                                          \
    e3 = exp2a(av0[3] * ub2f(gw0, 3));                                          \
    ssum += (e0 + e1) + (e2 + e3);                                              \
    p00 = cvtpk(e0, e1); p01 = cvtpk(e2, e3);                                   \
    e0 = exp2a(av1[0] * ub2f(gw1, 0));                                          \
    e1 = exp2a(av1[1] * ub2f(gw1, 1));                                          \
    e2 = exp2a(av1[2] * ub2f(gw1, 2));                                          \
    e3 = exp2a(av1[3] * ub2f(gw1, 3));                                          \
    ssum += (e0 + e1) + (e2 + e3);                                              \
    p10 = cvtpk(e0, e1); p11 = cvtpk(e2, e3);                                   \
    e0 = exp2a(av2[0] * ub2f(gw2, 0));                                          \
    e1 = exp2a(av2[1] * ub2f(gw2, 1));                                          \
    e2 = exp2a(av2[2] * ub2f(gw2, 2));                                          \
    e3 = exp2a(av2[3] * ub2f(gw2, 3));                                          \
    ssum += (e0 + e1) + (e2 + e3);                                              \
    p20 = cvtpk(e0, e1); p21 = cvtpk(e2, e3);                                   \
    e0 = exp2a(av3[0] * ub2f(gw3, 0));                                          \
    e1 = exp2a(av3[1] * ub2f(gw3, 1));                                          \
    e2 = exp2a(av3[2] * ub2f(gw3, 2));                                          \
    e3 = exp2a(av3[3] * ub2f(gw3, 3));                                          \
    ssum += (e0 + e1) + (e2 + e3);                                              \
    p30 = cvtpk(e0, e1); p31 = cvtpk(e2, e3);                                   \
    s16x8 pf0 = pack4(p00, p01, p10, p11);                                      \
    s16x8 pf1 = pack4(p20, p21, p30, p31);                                      \
    ov_a = __builtin_amdgcn_mfma_f32_16x16x32_bf16(                             \
        *(const s16x8*)&VL[((SC) * 2 + 0) * 512 + lane * 8], pf0, ov_a, 0, 0, 0); \
    ov_b = __builtin_amdgcn_mfma_f32_16x16x32_bf16(                             \
        *(const s16x8*)&VL[(8 + (SC) * 2 + 0) * 512 + lane * 8], pf0, ov_b, 0, 0, 0); \
    ov_a = __builtin_amdgcn_mfma_f32_16x16x32_bf16(                             \
        *(const s16x8*)&VL[((SC) * 2 + 1) * 512 + lane * 8], pf1, ov_a, 0, 0, 0); \
    ov_b = __builtin_amdgcn_mfma_f32_16x16x32_bf16(                             \
        *(const s16x8*)&VL[(8 + (SC) * 2 + 1) * 512 + lane * 8], pf1, ov_b, 0, 0, 0); \
  }

// m97-style chunk: issue next stage, compute current, ONE __syncthreads().
#define CHUNK(MM)                                                               \
  {                                                                             \
    if ((MM) < 7) stage_chunk(KfG, VfG, lds0, ((MM) + 1) & 1, l, b,             \
                              ((MM) + 1) >> 1, ((MM) + 1) & 1, wave, lane);     \
    const unsigned short* KL = &lds[(MM) & 1][0];                               \
    const unsigned short* VL = &lds[(MM) & 1][8192];                            \
    SCSTEP(MM, 0) SCSTEP(MM, 1) SCSTEP(MM, 2) SCSTEP(MM, 3)                     \
    if ((MM) < 7) __syncthreads();                                              \
  }

// per-head block: acc scoped to exactly this head's two chunks
#define HBLOCK(H)                                                               \
  {                                                                             \
    f32x4 ov_a = zf, ov_b = zf;                                                 \
    float ssum = 0.f;                                                           \
    CHUNK(2 * (H)) CHUNK(2 * (H) + 1)                                           \
    ssum += __shfl_xor(ssum, 16, 64);                                           \
    ssum += __shfl_xor(ssum, 32, 64);                                           \
    float inv = 1.f / ssum;                                                     \
    pfO[H] = pack4(cvtpk(ov_a[0] * inv, ov_a[1] * inv),                         \
                   cvtpk(ov_a[2] * inv, ov_a[3] * inv),                         \
                   cvtpk(ov_b[0] * inv, ov_b[1] * inv),                         \
                   cvtpk(ov_b[2] * inv, ov_b[3] * inv));                        \
  }

// ---- megakernel: both layers. block = (64 g-rows, b), 4 waves x 16 rows.
__global__ __launch_bounds__(256, 2) void mega_kern(
    const int* __restrict__ gene_idx, const float* __restrict__ expr,
    const float* __restrict__ gene_emb, const unsigned short* __restrict__ WtAll,
    const float* __restrict__ bq, const float* __restrict__ bo,
    const unsigned short* __restrict__ KfG, const unsigned short* __restrict__ VfG,
    const unsigned char* __restrict__ Mgu, float* __restrict__ partial) {
  __shared__ unsigned short lds[2][16384];  // 64 KB double buffer
  int bid = blockIdx.x;
  int xcd = bid & 7, wi = bid >> 3;
  int b = xcd * 2 + (wi >> 5);              // each XCD owns 2 b's (KV L2 locality)
  int gt = wi & 31;
  int tid = threadIdx.x, lane = tid & 63, wave = tid >> 6;
  int lg = lane >> 4, gg = lane & 15;
  int grow = gt * 64 + wave * 16 + gg;
  int growc = grow < 2000 ? grow : 1999;
  int row = b * 2000 + growc;
  const f32x4 zf = (f32x4){0.f, 0.f, 0.f, 0.f};
  const float GQ = 0.17677669529663687f * 1.4426950408889634f / 255.f;  // folded into Q

  // gate fragments (pi-permuted, u8): resident (streaming NaN'd in v10/v13)
  uint4 gu[8];
  {
    const unsigned char* gbase = Mgu + (size_t)growc * 512 + lg * 16;
#pragma unroll
    for (int sub = 0; sub < 8; ++sub)
      gu[sub] = *(const uint4*)(gbase + sub * 64);
  }
  // x0 fragments in kappa2 slots (d = 32c + 4lg + (j&3) + 16*(j>>2))
  s16x8 xf[4];
  {
    int gi = gene_idx[row];
    float ev = expr[row];
    const float* src = gene_emb + (size_t)gi * 128 + lg * 4;
#pragma unroll
    for (int c = 0; c < 4; ++c) {
      float4 u0 = *(const float4*)&src[c * 32];
      float4 u1 = *(const float4*)&src[c * 32 + 16];
      xf[c] = pack4(cvtpk(u0.x * ev, u0.y * ev), cvtpk(u0.z * ev, u0.w * ev),
                    cvtpk(u1.x * ev, u1.y * ev), cvtpk(u1.z * ev, u1.w * ev));
    }
  }

  unsigned short* lds0 = &lds[0][0];

#pragma unroll 1
  for (int l = 0; l < 2; ++l) {
    const unsigned short* WqFl = WtAll + (l * 4 + 0) * 16384;
    const unsigned short* WoFl = WtAll + (l * 4 + 3) * 16384;
    const float* bql = bq + l * 128;
    const float* bol = bo + l * 128;

    stage_chunk(KfG, VfG, lds0, 0, l, b, 0, 0, wave, lane);  // prefetch chunk 0

    // Q projection (register-only; overlaps chunk-0 load latency)
    s16x8 qf[4];
    {
      f32x4 qacc[8];
#pragma unroll
      for (int nt = 0; nt < 8; ++nt) {
        f32x4 acc = zf;
#pragma unroll
        for (int c = 0; c < 4; ++c) {
          s16x8 wf = *(const s16x8*)&WqFl[((nt * 4 + c) << 9) + lane * 8];
          acc = __builtin_amdgcn_mfma_f32_16x16x32_bf16(wf, xf[c], acc, 0, 0, 0);
        }
        float4 b4 = *(const float4*)&bql[nt * 16 + lg * 4];
        acc[0] = (acc[0] + b4.x) * GQ;
        acc[1] = (acc[1] + b4.y) * GQ;
        acc[2] = (acc[2] + b4.z) * GQ;
        acc[3] = (acc[3] + b4.w) * GQ;
        qacc[nt] = acc;
      }
#pragma unroll
      for (int h = 0; h < 4; ++h)
        qf[h] = pack4(cvtpk(qacc[2 * h][0], qacc[2 * h][1]), cvtpk(qacc[2 * h][2], qacc[2 * h][3]),
                      cvtpk(qacc[2 * h + 1][0], qacc[2 * h + 1][1]), cvtpk(qacc[2 * h + 1][2], qacc[2 * h + 1][3]));
    }
    __syncthreads();   // chunk 0 staged

    s16x8 pfO[4];
    HBLOCK(0) HBLOCK(1) HBLOCK(2) HBLOCK(3)

    // O projection: x^T = WoF * O^T (kappa2), + bo
    f32x4 xacc[8];
#pragma unroll
    for (int nt = 0; nt < 8; ++nt) {
      f32x4 acc = zf;
#pragma unroll
      for (int c = 0; c < 4; ++c) {
        s16x8 wf = *(const s16x8*)&WoFl[((nt * 4 + c) << 9) + lane * 8];
        acc = __builtin_amdgcn_mfma_f32_16x16x32_bf16(wf, pfO[c], acc, 0, 0, 0);
      }
      float4 b4 = *(const float4*)&bol[nt * 16 + lg * 4];
      acc[0] += b4.x; acc[1] += b4.y; acc[2] += b4.z; acc[3] += b4.w;
      xacc[nt] = acc;
    }

    if (l == 0) {
      // x1 stays in registers: rename acc -> kappa2 B-frags for layer-1 Q-proj
#pragma unroll
      for (int c = 0; c < 4; ++c)
        xf[c] = pack4(cvtpk(xacc[2 * c][0], xacc[2 * c][1]), cvtpk(xacc[2 * c][2], xacc[2 * c][3]),
                      cvtpk(xacc[2 * c + 1][0], xacc[2 * c + 1][1]), cvtpk(xacc[2 * c + 1][2], xacc[2 * c + 1][3]));
    } else {
      // fold mean-over-g: f32 column sums -> partial[b][gt][128]
      if (grow >= 2000) {
#pragma unroll
        for (int nt = 0; nt < 8; ++nt) xacc[nt] = zf;
      }
#pragma unroll
      for (int nt = 0; nt < 8; ++nt) {
#pragma unroll
        for (int msk = 1; msk <= 8; msk <<= 1) {
          xacc[nt][0] += __shfl_xor(xacc[nt][0], msk, 64);
          xacc[nt][1] += __shfl_xor(xacc[nt][1], msk, 64);
          xacc[nt][2] += __shfl_xor(xacc[nt][2], msk, 64);
          xacc[nt][3] += __shfl_xor(xacc[nt][3], msk, 64);
        }
      }
      float* red = (float*)lds0;
      __syncthreads();   // all waves done reading LDS K/V buffers
      if (gg == 0) {
#pragma unroll
        for (int nt = 0; nt < 8; ++nt) {
          red[wave * 128 + nt * 16 + lg * 4 + 0] = xacc[nt][0];
          red[wave * 128 + nt * 16 + lg * 4 + 1] = xacc[nt][1];
          red[wave * 128 + nt * 16 + lg * 4 + 2] = xacc[nt][2];
          red[wave * 128 + nt * 16 + lg * 4 + 3] = xacc[nt][3];
        }
      }
      __syncthreads();
      if (tid < 128) {
        float s = red[tid] + red[128 + tid] + red[256 + tid] + red[384 + tid];
        partial[((size_t)b * 32 + gt) * 128 + tid] = s;
      }
    }
  }
}

// ---- out[b][p] = mean_d @ W_out + b_out  (f32)
__global__ void final_out(const float* __restrict__ partial, const float* __restrict__ W_out,
                          const float* __restrict__ b_out, float* __restrict__ out) {
  int b = blockIdx.x, tid = threadIdx.x;
  __shared__ float mean[128];
  if (tid < 128) {
    float s = 0.f;
    for (int c = 0; c < 32; c++) s += partial[((size_t)b * 32 + c) * 128 + tid];
    mean[tid] = s * (1.f / 2000.f);
  }
  __syncthreads();
  for (int p = tid; p < 512; p += 256) {
    float a = b_out[p];
    for (int d = 0; d < 128; d++) a += mean[d] * W_out[d * 512 + p];
    out[b * 512 + p] = a;
  }
}

extern "C" void kernel_launch(void* const* d_in, const int* in_sizes, int n_in,
                              void* d_out, int out_size, void* d_ws, size_t ws_size,
                              hipStream_t stream) {
  const int*   gene_idx = (const int*)d_in[0];
  const float* expr     = (const float*)d_in[1];
  const int*   pw_idx   = (const int*)d_in[2];
  const float* W_soft   = (const float*)d_in[3];
  const float* gene_emb = (const float*)d_in[4];
  const float* pw_emb   = (const float*)d_in[5];
  const float* Wq = (const float*)d_in[6];
  const float* bq = (const float*)d_in[7];
  const float* Wk = (const float*)d_in[8];
  const float* bk = (const float*)d_in[9];
  const float* Wv = (const float*)d_in[10];
  const float* bv = (const float*)d_in[11];
  const float* Wo = (const float*)d_in[12];
  const float* bo = (const float*)d_in[13];
  const float* W_out = (const float*)d_in[14];
  const float* b_out = (const float*)d_in[15];
  float* out = (float*)d_out;

  char* ws = (char*)d_ws;
  size_t off = 0;
  auto alloc = [&](size_t bytes) {
    char* p = ws + off;
    off += (bytes + 255) & ~(size_t)255;
    return p;
  };
  unsigned char*  Mgu   = (unsigned char*)alloc((size_t)2048 * 512);               // 1 MB
  unsigned short* WtAll = (unsigned short*)alloc((size_t)8 * 16384 * 2);           // 256 KB
  unsigned short* KfG   = (unsigned short*)alloc((size_t)2 * 16 * 4 * 32 * 512 * 2);      // 4 MB
  unsigned short* VfG   = (unsigned short*)alloc((size_t)2 * 16 * 4 * 2 * 16 * 512 * 2);  // 4 MB
  float* partial        = (float*)alloc((size_t)16 * 32 * 128 * 4);                // 256 KB

  prep_wt<<<8, 256, 0, stream>>>(Wq, Wk, Wv, Wo, WtAll);
  prep_gate<<<250, 256, 0, stream>>>(gene_idx, W_soft, Mgu);
  kv_pack<<<2048, 64, 0, stream>>>(pw_idx, pw_emb, WtAll, bk, bv, KfG, VfG);
  mega_kern<<<512, 256, 0, stream>>>(gene_idx, expr, gene_emb, WtAll, bq, bo, KfG, VfG, Mgu, partial);
  final_out<<<16, 256, 0, stream>>>(partial, W_out, b_out, out);
}